// Round 9
// baseline (431.878 us; speedup 1.0000x reference)
//
#include <hip/hip_runtime.h>
#include <hip/hip_bf16.h>
#include <math.h>

typedef short short8 __attribute__((ext_vector_type(8)));
typedef float f32x4 __attribute__((ext_vector_type(4)));

__device__ __forceinline__ float sigf(float x) { return 1.f / (1.f + expf(-x)); }
__device__ __forceinline__ ushort f2bf(float f) {
    return __builtin_bit_cast(unsigned short, __float2bfloat16(f));
}

#define GLOAD16(gp, lp) \
    __builtin_amdgcn_global_load_lds((const __attribute__((address_space(1))) void*)(gp), \
                                     (__attribute__((address_space(3))) void*)(lp), 16, 0, 0)

// concatenated bf16 weight layout (ushort indices)
#define OFF_G0 0           // 3072 rows x K=1024 : [Wul(2048); Wur(1024)]
#define OFF_G1 3145728     // 5632 rows x K=2048 : [Wq;Wk;Wskip;Wv;Wo;Wi(8);Wf(8);zero(496)]
#define OFF_D  14680064    // 1024 rows x K=1024 : [Wd]
#define W_END  15728640

// ---------------- prep: LayerNorm (blocks 0-255) + weight cvt (blocks 256+) ----------
__global__ void prep_kernel(const float* __restrict__ seq, const float* __restrict__ ln_g,
                            const float* __restrict__ ln_b,
                            const float* __restrict__ Wul, const float* __restrict__ Wur,
                            const float* __restrict__ Wq, const float* __restrict__ Wk,
                            const float* __restrict__ Wskip, const float* __restrict__ Wv,
                            const float* __restrict__ Wo, const float* __restrict__ Wi,
                            const float* __restrict__ Wf, const float* __restrict__ Wd,
                            ushort* __restrict__ xnb, ushort* __restrict__ wbf) {
    int t = threadIdx.x;
    if (blockIdx.x < 256) {
        int b = blockIdx.x;
        const float* row = seq + (size_t)b * 1024;
        float4 v = *(const float4*)(row + t * 4);
        float s1 = v.x + v.y + v.z + v.w;
        float s2 = v.x * v.x + v.y * v.y + v.z * v.z + v.w * v.w;
        #pragma unroll
        for (int o = 32; o; o >>= 1) { s1 += __shfl_down(s1, o, 64); s2 += __shfl_down(s2, o, 64); }
        __shared__ float r1[4], r2[4];
        __shared__ float mu_s, rs_s;
        int wid = t >> 6, lane = t & 63;
        if (lane == 0) { r1[wid] = s1; r2[wid] = s2; }
        __syncthreads();
        if (t == 0) {
            float S1 = r1[0] + r1[1] + r1[2] + r1[3];
            float S2 = r2[0] + r2[1] + r2[2] + r2[3];
            float mu = S1 / 1024.f;
            mu_s = mu;
            rs_s = rsqrtf(S2 / 1024.f - mu * mu + 1e-5f);
        }
        __syncthreads();
        float mu = mu_s, rs = rs_s;
        float4 gg = *(const float4*)(ln_g + t * 4);
        float4 bb = *(const float4*)(ln_b + t * 4);
        ushort4 o4;
        o4.x = f2bf((v.x - mu) * rs * gg.x + bb.x);
        o4.y = f2bf((v.y - mu) * rs * gg.y + bb.y);
        o4.z = f2bf((v.z - mu) * rs * gg.z + bb.z);
        o4.w = f2bf((v.w - mu) * rs * gg.w + bb.w);
        *(ushort4*)(xnb + (size_t)b * 1024 + t * 4) = o4;
    } else {
        size_t e = ((size_t)(blockIdx.x - 256) * 256 + t) * 8;
        const float* sp = nullptr;
        if (e < OFF_G1) {
            size_t row = e >> 10, col = e & 1023;
            sp = (row < 2048 ? Wul + row * 1024 : Wur + (row - 2048) * 1024) + col;
        } else if (e < OFF_D) {
            size_t rel = e - OFF_G1;
            size_t row = rel >> 11, col = rel & 2047;
            if (row < 1024)      sp = Wq + row * 2048 + col;
            else if (row < 2048) sp = Wk + (row - 1024) * 2048 + col;
            else if (row < 3072) sp = Wskip + (row - 2048) * 2048 + col;
            else if (row < 4096) sp = Wv + (row - 3072) * 2048 + col;
            else if (row < 5120) sp = Wo + (row - 4096) * 2048 + col;
            else if (row < 5128) sp = Wi + (row - 5120) * 2048 + col;
            else if (row < 5136) sp = Wf + (row - 5128) * 2048 + col;
            else sp = nullptr;   // zero pad rows 5136-5631
        } else {
            sp = Wd + (e - OFF_D);
        }
        short8 r;
        if (sp) {
            f32x4 a = *(const f32x4*)sp;
            f32x4 b = *(const f32x4*)(sp + 4);
            r[0] = (short)f2bf(a[0]); r[1] = (short)f2bf(a[1]);
            r[2] = (short)f2bf(a[2]); r[3] = (short)f2bf(a[3]);
            r[4] = (short)f2bf(b[0]); r[5] = (short)f2bf(b[1]);
            r[6] = (short)f2bf(b[2]); r[7] = (short)f2bf(b[3]);
        } else {
            r = (short8){0,0,0,0,0,0,0,0};
        }
        *(short8*)(wbf + e) = r;
    }
}

// ---------------- g0: x_n @ [Wul;Wur]^T, K=1024, N=3072 (4-buf counted vmcnt) --------
__global__ void g_gemm0(const ushort* __restrict__ A, const ushort* __restrict__ Wb,
                        const float* __restrict__ bul, const float* __restrict__ bur,
                        float* __restrict__ x_t, float* __restrict__ sr,
                        ushort* __restrict__ xtb) {
    constexpr int K = 1024, NT = 16;
    __shared__ __align__(16) ushort As[4][4096];
    __shared__ __align__(16) ushort Bs[4][4096];
    int hwid = blockIdx.x;
    int xcd = hwid & 7, q = hwid >> 3;
    int mt = q & 3, g = ((q >> 2) << 3) + xcd;   // 192 = 8 x 4 x 6 bijective
    int bm = mt << 6, bn = g << 6;
    int tid = threadIdx.x;
    int w = tid >> 6, l = tid & 63;
    int wr = w >> 1, wc = w & 1;
    int lr = l & 15, lg = l >> 4;
    int si0 = tid, si1 = 256 + tid;
    int r0 = si0 >> 3, su0 = (si0 & 7) ^ (r0 & 7);
    int r1 = si1 >> 3, su1 = (si1 & 7) ^ (r1 & 7);
    const ushort* gA0 = A + (size_t)(bm + r0) * K + su0 * 8;
    const ushort* gA1 = A + (size_t)(bm + r1) * K + su1 * 8;
    const ushort* gB0 = Wb + (size_t)(bn + r0) * K + su0 * 8;
    const ushort* gB1 = Wb + (size_t)(bn + r1) * K + su1 * 8;
    f32x4 acc[2][2] = {};
    #pragma unroll
    for (int pt = 0; pt < 2; pt++) {
        int k0 = pt * 64;
        GLOAD16(gA0 + k0, &As[pt][si0 * 8]);
        GLOAD16(gA1 + k0, &As[pt][si1 * 8]);
        GLOAD16(gB0 + k0, &Bs[pt][si0 * 8]);
        GLOAD16(gB1 + k0, &Bs[pt][si1 * 8]);
    }
    for (int t = 0; t < NT; t++) {
        if (t + 2 < NT) {
            int k0 = (t + 2) * 64, nb = (t + 2) & 3;
            GLOAD16(gA0 + k0, &As[nb][si0 * 8]);
            GLOAD16(gA1 + k0, &As[nb][si1 * 8]);
            GLOAD16(gB0 + k0, &Bs[nb][si0 * 8]);
            GLOAD16(gB1 + k0, &Bs[nb][si1 * 8]);
            asm volatile("s_waitcnt vmcnt(8)" ::: "memory");
        } else if (t + 1 < NT) {
            asm volatile("s_waitcnt vmcnt(4)" ::: "memory");
        } else {
            asm volatile("s_waitcnt vmcnt(0)" ::: "memory");
        }
        __builtin_amdgcn_sched_barrier(0);
        __builtin_amdgcn_s_barrier();
        __builtin_amdgcn_sched_barrier(0);
        int cur = t & 3;
        const char* Ac = (const char*)As[cur];
        const char* Bc = (const char*)Bs[cur];
        short8 af[2][2], bfr[2][2];
        #pragma unroll
        for (int mi = 0; mi < 2; mi++)
            #pragma unroll
            for (int ks = 0; ks < 2; ks++) {
                int r = wr * 32 + mi * 16 + lr;
                int c = (ks * 64 + lg * 16) ^ ((r & 7) << 4);
                af[mi][ks] = *(const short8*)(Ac + r * 128 + c);
            }
        #pragma unroll
        for (int ni = 0; ni < 2; ni++)
            #pragma unroll
            for (int ks = 0; ks < 2; ks++) {
                int r = wc * 32 + ni * 16 + lr;
                int c = (ks * 64 + lg * 16) ^ ((r & 7) << 4);
                bfr[ni][ks] = *(const short8*)(Bc + r * 128 + c);
            }
        #pragma unroll
        for (int ks = 0; ks < 2; ks++)
            #pragma unroll
            for (int mi = 0; mi < 2; mi++)
                #pragma unroll
                for (int ni = 0; ni < 2; ni++)
                    acc[mi][ni] = __builtin_amdgcn_mfma_f32_16x16x32_bf16(
                        af[mi][ks], bfr[ni][ks], acc[mi][ni], 0, 0, 0);
        __builtin_amdgcn_sched_barrier(0);
    }
    #pragma unroll
    for (int mi = 0; mi < 2; mi++)
        #pragma unroll
        for (int ni = 0; ni < 2; ni++) {
            int n = bn + wc * 32 + ni * 16 + lr;
            #pragma unroll
            for (int r = 0; r < 4; r++) {
                int m = bm + wr * 32 + mi * 16 + lg * 4 + r;
                float val = acc[mi][ni][r];
                if (n < 2048) {
                    val += bul[n];
                    x_t[(size_t)m * 2048 + n] = val;
                    xtb[(size_t)m * 2048 + n] = f2bf(val);
                } else {
                    int nc = n - 2048;
                    val += bur[nc];
                    sr[(size_t)m * 1024 + nc] = val * sigf(val);
                }
            }
        }
}

// ---------------- g_mega: {x_c@[Wq;Wk;Wskip], x_t@[Wv;Wo], x_c@[Wi;Wf]} K=2048 ------
// N=5632 (padded). x_c segments compute conv+silu from x_t f32 during A-staging.
__global__ void g_mega(const float* __restrict__ xt_f32, const ushort* __restrict__ xtb,
                       const ushort* __restrict__ Wb,
                       const float* __restrict__ conv_w, const float* __restrict__ conv_b,
                       const float* __restrict__ bq, const float* __restrict__ bk,
                       const float* __restrict__ bv, const float* __restrict__ bo,
                       const float* __restrict__ bi, const float* __restrict__ bf2,
                       float* __restrict__ qb, float* __restrict__ kb,
                       float* __restrict__ skipb, float* __restrict__ vb,
                       float* __restrict__ ob, float* __restrict__ itb,
                       float* __restrict__ ftb) {
    constexpr int K = 2048, NT = 32;
    const float KSCALE = 0.088388347648318447f;
    __shared__ __align__(16) ushort As[4][4096];
    __shared__ __align__(16) ushort Bs[4][4096];
    int hwid = blockIdx.x;
    int xcd = hwid & 7, q = hwid >> 3;          // 352 = 8 x 4 x 11 bijective
    int mt = q & 3, gq = q >> 2;
    int g = gq * 8 + xcd;                        // 0..87
    int bm = mt << 6, bn = g << 6;
    bool is_xc = (bn < 3072) || (bn >= 5120);
    int tid = threadIdx.x;
    int w = tid >> 6, l = tid & 63;
    int wr = w >> 1, wc = w & 1;
    int lr = l & 15, lg = l >> 4;
    int si0 = tid, si1 = 256 + tid;
    int r0 = si0 >> 3, su0 = (si0 & 7) ^ (r0 & 7);
    int r1 = si1 >> 3, su1 = (si1 & 7) ^ (r1 & 7);
    const ushort* gB0 = Wb + (size_t)(bn + r0) * K + su0 * 8;
    const ushort* gB1 = Wb + (size_t)(bn + r1) * K + su1 * 8;
    f32x4 acc[2][2] = {};

    if (is_xc) {
        // ---- reg-staged A (conv+silu from x_t f32), 2-buf A, 4-buf B, 1 barrier/step
        float cw0 = conv_w[0], cw1 = conv_w[1], cw2 = conv_w[2], cw3 = conv_w[3];
        float cbias = conv_b[0];
        int ar = tid >> 2, ac4 = tid & 3;                  // row 0..63, 16-col chunk 0..3
        const float* arow = xt_f32 + (size_t)(bm + ar) * 2048;
        int au0 = ((ac4 * 2) ^ (ar & 7)) << 4;             // swizzled byte chunks
        int au1 = ((ac4 * 2 + 1) ^ (ar & 7)) << 4;
        // B first (so reg-load waits imply B done via in-order vmcnt retirement)
        GLOAD16(gB0, &Bs[0][si0 * 8]);
        GLOAD16(gB1, &Bs[0][si1 * 8]);
        GLOAD16(gB0 + 64, &Bs[1][si0 * 8]);
        GLOAD16(gB1 + 64, &Bs[1][si1 * 8]);
        f32x4 pv0, pv1, pv2, pv3, pv4;
        {
            const float* ap = arow + ac4 * 16;
            if (ac4 == 0) pv0 = (f32x4){0.f, 0.f, 0.f, 0.f};
            else          pv0 = *(const f32x4*)(ap - 4);
            pv1 = *(const f32x4*)(ap);
            pv2 = *(const f32x4*)(ap + 4);
            pv3 = *(const f32x4*)(ap + 8);
            pv4 = *(const f32x4*)(ap + 12);
        }
        for (int t = 0; t < NT; t++) {
            f32x4 nv0, nv1, nv2, nv3, nv4;
            if (t + 1 < NT) {
                const float* ap = arow + (t + 1) * 64 + ac4 * 16;
                nv0 = *(const f32x4*)(ap - 4);
                nv1 = *(const f32x4*)(ap);
                nv2 = *(const f32x4*)(ap + 4);
                nv3 = *(const f32x4*)(ap + 8);
                nv4 = *(const f32x4*)(ap + 12);
            }
            if (t + 2 < NT) {
                int kk = (t + 2) * 64, nb = (t + 2) & 3;
                GLOAD16(gB0 + kk, &Bs[nb][si0 * 8]);
                GLOAD16(gB1 + kk, &Bs[nb][si1 * 8]);
            }
            // conv + silu on prev window (compiler waits pv* -> implies B(t) retired)
            float Wv_[20];
            *(f32x4*)(Wv_ + 0)  = pv0; *(f32x4*)(Wv_ + 4)  = pv1;
            *(f32x4*)(Wv_ + 8)  = pv2; *(f32x4*)(Wv_ + 12) = pv3;
            *(f32x4*)(Wv_ + 16) = pv4;
            short8 p0, p1;
            #pragma unroll
            for (int j = 0; j < 16; j++) {
                float a = fmaf(cw3, Wv_[j + 4], fmaf(cw2, Wv_[j + 3],
                          fmaf(cw1, Wv_[j + 2], fmaf(cw0, Wv_[j + 1], cbias))));
                a = a * (1.f / (1.f + expf(-a)));
                if (j < 8) p0[j] = (short)f2bf(a); else p1[j - 8] = (short)f2bf(a);
            }
            char* Aw = (char*)As[t & 1] + ar * 128;
            *(short8*)(Aw + au0) = p0;
            *(short8*)(Aw + au1) = p1;
            asm volatile("s_waitcnt lgkmcnt(0)" ::: "memory");
            __builtin_amdgcn_sched_barrier(0);
            __builtin_amdgcn_s_barrier();
            __builtin_amdgcn_sched_barrier(0);
            const char* Ac = (const char*)As[t & 1];
            const char* Bc = (const char*)Bs[t & 3];
            short8 af[2][2], bfr[2][2];
            #pragma unroll
            for (int mi = 0; mi < 2; mi++)
                #pragma unroll
                for (int ks = 0; ks < 2; ks++) {
                    int r = wr * 32 + mi * 16 + lr;
                    int c = (ks * 64 + lg * 16) ^ ((r & 7) << 4);
                    af[mi][ks] = *(const short8*)(Ac + r * 128 + c);
                }
            #pragma unroll
            for (int ni = 0; ni < 2; ni++)
                #pragma unroll
                for (int ks = 0; ks < 2; ks++) {
                    int r = wc * 32 + ni * 16 + lr;
                    int c = (ks * 64 + lg * 16) ^ ((r & 7) << 4);
                    bfr[ni][ks] = *(const short8*)(Bc + r * 128 + c);
                }
            #pragma unroll
            for (int ks = 0; ks < 2; ks++)
                #pragma unroll
                for (int mi = 0; mi < 2; mi++)
                    #pragma unroll
                    for (int ni = 0; ni < 2; ni++)
                        acc[mi][ni] = __builtin_amdgcn_mfma_f32_16x16x32_bf16(
                            af[mi][ks], bfr[ni][ks], acc[mi][ni], 0, 0, 0);
            pv0 = nv0; pv1 = nv1; pv2 = nv2; pv3 = nv3; pv4 = nv4;
            __builtin_amdgcn_sched_barrier(0);
        }
    } else {
        // ---- V/O path: both A and B via 4-buf counted-vmcnt DMA (round-7 structure)
        const ushort* gA0 = xtb + (size_t)(bm + r0) * K + su0 * 8;
        const ushort* gA1 = xtb + (size_t)(bm + r1) * K + su1 * 8;
        #pragma unroll
        for (int pt = 0; pt < 2; pt++) {
            int k0 = pt * 64;
            GLOAD16(gA0 + k0, &As[pt][si0 * 8]);
            GLOAD16(gA1 + k0, &As[pt][si1 * 8]);
            GLOAD16(gB0 + k0, &Bs[pt][si0 * 8]);
            GLOAD16(gB1 + k0, &Bs[pt][si1 * 8]);
        }
        for (int t = 0; t < NT; t++) {
            if (t + 2 < NT) {
                int k0 = (t + 2) * 64, nb = (t + 2) & 3;
                GLOAD16(gA0 + k0, &As[nb][si0 * 8]);
                GLOAD16(gA1 + k0, &As[nb][si1 * 8]);
                GLOAD16(gB0 + k0, &Bs[nb][si0 * 8]);
                GLOAD16(gB1 + k0, &Bs[nb][si1 * 8]);
                asm volatile("s_waitcnt vmcnt(8)" ::: "memory");
            } else if (t + 1 < NT) {
                asm volatile("s_waitcnt vmcnt(4)" ::: "memory");
            } else {
                asm volatile("s_waitcnt vmcnt(0)" ::: "memory");
            }
            __builtin_amdgcn_sched_barrier(0);
            __builtin_amdgcn_s_barrier();
            __builtin_amdgcn_sched_barrier(0);
            int cur = t & 3;
            const char* Ac = (const char*)As[cur];
            const char* Bc = (const char*)Bs[cur];
            short8 af[2][2], bfr[2][2];
            #pragma unroll
            for (int mi = 0; mi < 2; mi++)
                #pragma unroll
                for (int ks = 0; ks < 2; ks++) {
                    int r = wr * 32 + mi * 16 + lr;
                    int c = (ks * 64 + lg * 16) ^ ((r & 7) << 4);
                    af[mi][ks] = *(const short8*)(Ac + r * 128 + c);
                }
            #pragma unroll
            for (int ni = 0; ni < 2; ni++)
                #pragma unroll
                for (int ks = 0; ks < 2; ks++) {
                    int r = wc * 32 + ni * 16 + lr;
                    int c = (ks * 64 + lg * 16) ^ ((r & 7) << 4);
                    bfr[ni][ks] = *(const short8*)(Bc + r * 128 + c);
                }
            #pragma unroll
            for (int ks = 0; ks < 2; ks++)
                #pragma unroll
                for (int mi = 0; mi < 2; mi++)
                    #pragma unroll
                    for (int ni = 0; ni < 2; ni++)
                        acc[mi][ni] = __builtin_amdgcn_mfma_f32_16x16x32_bf16(
                            af[mi][ks], bfr[ni][ks], acc[mi][ni], 0, 0, 0);
            __builtin_amdgcn_sched_barrier(0);
        }
    }

    // ---- epilogue
    int seg = bn >> 10;   // 0:q 1:k 2:skip 3:v 4:o 5:gates/pad
    #pragma unroll
    for (int mi = 0; mi < 2; mi++)
        #pragma unroll
        for (int ni = 0; ni < 2; ni++) {
            int n = bn + wc * 32 + ni * 16 + lr;
            #pragma unroll
            for (int r = 0; r < 4; r++) {
                int m = bm + wr * 32 + mi * 16 + lg * 4 + r;
                float val = acc[mi][ni][r];
                if (seg == 0) {
                    qb[(size_t)m * 1024 + n] = val + bq[n];
                } else if (seg == 1) {
                    int nc = n - 1024;
                    kb[(size_t)m * 1024 + nc] = (val + bk[nc]) * KSCALE;
                } else if (seg == 2) {
                    skipb[(size_t)m * 1024 + (n - 2048)] = val;
                } else if (seg == 3) {
                    int nc = n - 3072;
                    vb[(size_t)m * 1024 + nc] = val + bv[nc];
                } else if (seg == 4) {
                    int nc = n - 4096;
                    ob[(size_t)m * 1024 + nc] = sigf(val + bo[nc]);
                } else {
                    int j = n - 5120;
                    if (j < 8)       itb[m * 8 + j] = val + bi[j];
                    else if (j < 16) ftb[m * 8 + (j - 8)] = val + bf2[j - 8];
                }
            }
        }
}

// ---------------- Fused cell: c/n/m update, q-readout, groupnorm, skip, r-gate ------
__global__ void cell_kernel(const float* __restrict__ q, const float* __restrict__ k,
                            const float* __restrict__ v, const float* __restrict__ o,
                            const float* __restrict__ i_t, const float* __restrict__ f_t,
                            const float* __restrict__ m_tm1, const float* __restrict__ n_tm1,
                            const float* __restrict__ c_tm1,
                            const float* __restrict__ gn_g, const float* __restrict__ gn_b,
                            const float* __restrict__ skip, const float* __restrict__ sr,
                            float* __restrict__ c_out, float* __restrict__ n_out,
                            float* __restrict__ m_out, ushort* __restrict__ y) {
    int bh = blockIdx.x;  // 0..2047
    int h = bh & 7;
    int t = threadIdx.x;
    __shared__ __align__(16) float qs[128];
    __shared__ __align__(16) float ks[128];
    __shared__ __align__(16) float vs[128];
    __shared__ float hnum[128];
    __shared__ float redA[4], redB[4];
    __shared__ float dsh, mu_s, rs_s;

    float fi = i_t[bh], ff = f_t[bh], mo = m_tm1[bh];
    float mt = fmaxf(ff + mo, fi);
    float ie = expf(fi - mt);
    float fe = expf(ff - mt + mo);
    if (t == 0) m_out[bh] = mt;

    int base = bh << 7;
    if (t < 128) { qs[t] = q[base + t]; ks[t] = k[base + t]; vs[t] = v[base + t]; }
    __syncthreads();

    float dn = 0.f;
    if (t < 128) {
        float nt = fe * n_tm1[base + t] + ie * ks[t];
        n_out[base + t] = nt;
        dn = nt * qs[t];
    }
    #pragma unroll
    for (int off2 = 32; off2; off2 >>= 1) dn += __shfl_down(dn, off2, 64);
    int wid = t >> 6, lane = t & 63;
    if (lane == 0) redA[wid] = dn;
    __syncthreads();
    if (t == 0) dsh = fmaxf(redA[0] + redA[1], 1.f);

    const float* cin = c_tm1 + ((size_t)bh << 14);
    float* cout = c_out + ((size_t)bh << 14);
    int l32 = t & 31, grp = t >> 5;
    float4 k4 = *(const float4*)&ks[l32 << 2];
    float4 q4 = *(const float4*)&qs[l32 << 2];
    #pragma unroll
    for (int it2 = 0; it2 < 16; ++it2) {
        int d = (it2 << 3) + grp;
        float vd = vs[d] * ie;
        int off = (d << 7) + (l32 << 2);
        float4 c4 = *(const float4*)(cin + off);
        float4 ct;
        ct.x = fmaf(fe, c4.x, vd * k4.x);
        ct.y = fmaf(fe, c4.y, vd * k4.y);
        ct.z = fmaf(fe, c4.z, vd * k4.z);
        ct.w = fmaf(fe, c4.w, vd * k4.w);
        *(float4*)(cout + off) = ct;
        float p = ct.x * q4.x + ct.y * q4.y + ct.z * q4.z + ct.w * q4.w;
        #pragma unroll
        for (int o2 = 16; o2; o2 >>= 1) p += __shfl_xor(p, o2, 32);
        if (l32 == 0) hnum[d] = p;
    }
    __syncthreads();

    float hval = 0.f;
    if (t < 128) hval = o[base + t] * hnum[t] / dsh;
    float s1 = hval, s2 = hval * hval;
    #pragma unroll
    for (int off2 = 32; off2; off2 >>= 1) { s1 += __shfl_down(s1, off2, 64); s2 += __shfl_down(s2, off2, 64); }
    if (lane == 0) { redA[wid] = s1; redB[wid] = s2; }
    __syncthreads();
    if (t == 0) {
        float S1 = redA[0] + redA[1], S2 = redB[0] + redB[1];
        float mu = S1 / 128.f;
        mu_s = mu;
        rs_s = rsqrtf(S2 / 128.f - mu * mu + 1e-5f);
    }
    __syncthreads();
    if (t < 128) {
        float xn = (hval - mu_s) * rs_s;
        int gi = (h << 7) + t;
        y[base + t] = f2bf((xn * gn_g[gi] + gn_b[gi] + skip[base + t]) * sr[base + t]);
    }
}

// ---------------- gD: y @ Wd^T + bd + seq, K=1024, N=1024 ---------------------------
__global__ void g_gemmD(const ushort* __restrict__ A, const ushort* __restrict__ Wb,
                        const float* __restrict__ bd, const float* __restrict__ seq,
                        float* __restrict__ out) {
    constexpr int K = 1024, NT = 16;
    __shared__ __align__(16) ushort As[4][4096];
    __shared__ __align__(16) ushort Bs[4][4096];
    int hwid = blockIdx.x;
    int xcd = hwid & 7, q = hwid >> 3;
    int mt = q & 3, g = ((q >> 2) << 3) + xcd;   // 64 = 8 x 4 x 2 bijective
    int bm = mt << 6, bn = g << 6;
    int tid = threadIdx.x;
    int w = tid >> 6, l = tid & 63;
    int wr = w >> 1, wc = w & 1;
    int lr = l & 15, lg = l >> 4;
    int si0 = tid, si1 = 256 + tid;
    int r0 = si0 >> 3, su0 = (si0 & 7) ^ (r0 & 7);
    int r1 = si1 >> 3, su1 = (si1 & 7) ^ (r1 & 7);
    const ushort* gA0 = A + (size_t)(bm + r0) * K + su0 * 8;
    const ushort* gA1 = A + (size_t)(bm + r1) * K + su1 * 8;
    const ushort* gB0 = Wb + (size_t)(bn + r0) * K + su0 * 8;
    const ushort* gB1 = Wb + (size_t)(bn + r1) * K + su1 * 8;
    f32x4 acc[2][2] = {};
    #pragma unroll
    for (int pt = 0; pt < 2; pt++) {
        int k0 = pt * 64;
        GLOAD16(gA0 + k0, &As[pt][si0 * 8]);
        GLOAD16(gA1 + k0, &As[pt][si1 * 8]);
        GLOAD16(gB0 + k0, &Bs[pt][si0 * 8]);
        GLOAD16(gB1 + k0, &Bs[pt][si1 * 8]);
    }
    for (int t = 0; t < NT; t++) {
        if (t + 2 < NT) {
            int k0 = (t + 2) * 64, nb = (t + 2) & 3;
            GLOAD16(gA0 + k0, &As[nb][si0 * 8]);
            GLOAD16(gA1 + k0, &As[nb][si1 * 8]);
            GLOAD16(gB0 + k0, &Bs[nb][si0 * 8]);
            GLOAD16(gB1 + k0, &Bs[nb][si1 * 8]);
            asm volatile("s_waitcnt vmcnt(8)" ::: "memory");
        } else if (t + 1 < NT) {
            asm volatile("s_waitcnt vmcnt(4)" ::: "memory");
        } else {
            asm volatile("s_waitcnt vmcnt(0)" ::: "memory");
        }
        __builtin_amdgcn_sched_barrier(0);
        __builtin_amdgcn_s_barrier();
        __builtin_amdgcn_sched_barrier(0);
        int cur = t & 3;
        const char* Ac = (const char*)As[cur];
        const char* Bc = (const char*)Bs[cur];
        short8 af[2][2], bfr[2][2];
        #pragma unroll
        for (int mi = 0; mi < 2; mi++)
            #pragma unroll
            for (int ks = 0; ks < 2; ks++) {
                int r = wr * 32 + mi * 16 + lr;
                int c = (ks * 64 + lg * 16) ^ ((r & 7) << 4);
                af[mi][ks] = *(const short8*)(Ac + r * 128 + c);
            }
        #pragma unroll
        for (int ni = 0; ni < 2; ni++)
            #pragma unroll
            for (int ks = 0; ks < 2; ks++) {
                int r = wc * 32 + ni * 16 + lr;
                int c = (ks * 64 + lg * 16) ^ ((r & 7) << 4);
                bfr[ni][ks] = *(const short8*)(Bc + r * 128 + c);
            }
        #pragma unroll
        for (int ks = 0; ks < 2; ks++)
            #pragma unroll
            for (int mi = 0; mi < 2; mi++)
                #pragma unroll
                for (int ni = 0; ni < 2; ni++)
                    acc[mi][ni] = __builtin_amdgcn_mfma_f32_16x16x32_bf16(
                        af[mi][ks], bfr[ni][ks], acc[mi][ni], 0, 0, 0);
        __builtin_amdgcn_sched_barrier(0);
    }
    #pragma unroll
    for (int mi = 0; mi < 2; mi++)
        #pragma unroll
        for (int ni = 0; ni < 2; ni++) {
            int n = bn + wc * 32 + ni * 16 + lr;
            #pragma unroll
            for (int r = 0; r < 4; r++) {
                int m = bm + wr * 32 + mi * 16 + lg * 4 + r;
                out[(size_t)m * 1024 + n] = acc[mi][ni][r] + bd[n] + seq[(size_t)m * 1024 + n];
            }
        }
}

extern "C" void kernel_launch(void* const* d_in, const int* in_sizes, int n_in,
                              void* d_out, int out_size, void* d_ws, size_t ws_size,
                              hipStream_t stream) {
    const float* seq    = (const float*)d_in[0];
    const float* c_tm1  = (const float*)d_in[1];
    const float* n_tm1  = (const float*)d_in[2];
    const float* m_tm1  = (const float*)d_in[3];
    const float* ln_g   = (const float*)d_in[4];
    const float* ln_b   = (const float*)d_in[5];
    const float* Wul    = (const float*)d_in[6];
    const float* bul    = (const float*)d_in[7];
    const float* Wur    = (const float*)d_in[8];
    const float* bur    = (const float*)d_in[9];
    const float* conv_w = (const float*)d_in[10];
    const float* conv_b = (const float*)d_in[11];
    const float* Wskip  = (const float*)d_in[12];
    const float* Wi     = (const float*)d_in[13];
    const float* bi     = (const float*)d_in[14];
    const float* Wf     = (const float*)d_in[15];
    const float* bf     = (const float*)d_in[16];
    const float* Wo     = (const float*)d_in[17];
    const float* bo     = (const float*)d_in[18];
    const float* Wq     = (const float*)d_in[19];
    const float* bq     = (const float*)d_in[20];
    const float* Wk     = (const float*)d_in[21];
    const float* bk     = (const float*)d_in[22];
    const float* Wv     = (const float*)d_in[23];
    const float* bv     = (const float*)d_in[24];
    const float* gn_g   = (const float*)d_in[25];
    const float* gn_b   = (const float*)d_in[26];
    const float* Wd     = (const float*)d_in[27];
    const float* bd     = (const float*)d_in[28];

    float* out   = (float*)d_out;          // [256,1024]
    float* c_out = out + 262144;           // [256,8,128,128]
    float* n_out = c_out + 33554432;       // [256,8,128]
    float* m_out = n_out + 262144;         // [256,8]

    float* ws    = (float*)d_ws;
    float*  x_t  = ws;                           // 524288 f32
    ushort* xnb  = (ushort*)(ws + 524288);       // 262144 bf16
    ushort* xtb  = (ushort*)(ws + 655360);       // 524288 bf16
    float*  sr   = ws + 917504;                  // 262144 f32
    float*  qb   = ws + 1179648;                 // 262144
    float*  kb   = ws + 1441792;
    float*  vb   = ws + 1703936;
    float*  ob   = ws + 1966080;
    float*  skipb= ws + 2228224;
    float*  itb  = ws + 2490368;                 // 2048
    float*  ftb  = ws + 2492416;                 // 2048
    ushort* ybf  = (ushort*)(ws + 2494464);      // 262144 bf16
    ushort* wbf  = (ushort*)(ws + 2625536);      // 15,728,640 bf16 (concat weights)

    dim3 blk(256);

    prep_kernel<<<7936, blk, 0, stream>>>(seq, ln_g, ln_b, Wul, Wur, Wq, Wk, Wskip,
                                          Wv, Wo, Wi, Wf, Wd, xnb, wbf);
    g_gemm0<<<192, blk, 0, stream>>>(xnb, wbf + OFF_G0, bul, bur, x_t, sr, xtb);
    g_mega<<<352, blk, 0, stream>>>(x_t, xtb, wbf + OFF_G1, conv_w, conv_b,
                                    bq, bk, bv, bo, bi, bf,
                                    qb, kb, skipb, vb, ob, itb, ftb);
    cell_kernel<<<2048, blk, 0, stream>>>(qb, kb, vb, ob, itb, ftb, m_tm1, n_tm1, c_tm1,
                                          gn_g, gn_b, skipb, sr, c_out, n_out, m_out, ybf);
    g_gemmD<<<64, blk, 0, stream>>>(ybf, wbf + OFF_D, bd, seq, out);
}